// Round 6
// baseline (99.618 us; speedup 1.0000x reference)
//
#include <hip/hip_runtime.h>

typedef __bf16 bf16x8 __attribute__((ext_vector_type(8)));
typedef float f32x4 __attribute__((ext_vector_type(4)));

#define MFMA(a, b, c) __builtin_amdgcn_mfma_f32_16x16x32_bf16(a, b, c, 0, 0, 0)

#define CS 0.18033688011112042f   /* 0.125 * log2(e) */

__device__ __forceinline__ ushort f2bf(float f) {
    __bf16 h = (__bf16)f;
    return *(ushort*)&h;
}

// ---- stage an (8*nchunks)-row x 64-col bf16 tile into LDS, XOR-swizzled ----
// LDS dest linear (global_load_lds requirement); per-lane GLOBAL source address
// pre-swizzled (m173 pattern). One 1KB chunk (8 rows x 128B) per wave-instr.
__device__ __forceinline__ void stage_tile64(ushort* lds, const ushort* gbase,
                                             int row_stride, int nchunks,
                                             int wave, int lane) {
    int r8 = lane >> 3;                       // row within 8-row chunk
    int cswz = ((lane & 7) ^ r8) << 4;        // pre-swizzled source byte col
#pragma unroll
    for (int c = wave; c < nchunks; c += 4) {
        const char* g = (const char*)(gbase + (size_t)(c * 8 + r8) * row_stride) + cswz;
        __builtin_amdgcn_global_load_lds(
            (const __attribute__((address_space(1))) unsigned int*)g,
            (__attribute__((address_space(3))) unsigned int*)((char*)lds + c * 1024),
            16, 0, 0);
    }
}

// swizzled read of logical (row, col-byte cb), 16B
__device__ __forceinline__ bf16x8 lds_read_row(const ushort* lds, int row, int cb) {
    return *(const bf16x8*)((const char*)lds + row * 128 + (cb ^ ((row & 7) << 4)));
}

// ---------------------------------------------------------------- groupnorm (+fused weight cvt)
// blocks [0,256): GroupNorm per (b,g); blocks [256,1280): fp32->bf16 weight cvt
__global__ __launch_bounds__(256) void gn_cvt_kernel(const float* __restrict__ x,
                                                     const float* __restrict__ gnw,
                                                     const float* __restrict__ gnb,
                                                     ushort* __restrict__ hnT,
                                                     const float* __restrict__ w1,
                                                     const float* __restrict__ w2,
                                                     ushort* __restrict__ o1,
                                                     ushort* __restrict__ o2) {
    if (blockIdx.x >= 256) {
        int t = (blockIdx.x - 256) * 256 + threadIdx.x;
        const int n1q = (1536 * 512) / 4;
        float4 v;
        ushort* dst;
        int idx;
        if (t < n1q) {
            v = ((const float4*)w1)[t]; dst = o1; idx = t;
        } else {
            idx = t - n1q;
            v = ((const float4*)w2)[idx]; dst = o2;
        }
        ushort4 p;
        p.x = f2bf(v.x); p.y = f2bf(v.y); p.z = f2bf(v.z); p.w = f2bf(v.w);
        ((ushort4*)dst)[idx] = p;
        return;
    }

    int b = blockIdx.x >> 5, g = blockIdx.x & 31;
    const float* xp = x + (size_t)(b * 512 + g * 16) * 1024;
    int t = threadIdx.x;

    float s = 0.f, ss = 0.f;
    const float4* xp4 = (const float4*)xp;
    for (int i = t; i < 4096; i += 256) {
        float4 v = xp4[i];
        s += (v.x + v.y) + (v.z + v.w);
        ss += (v.x * v.x + v.y * v.y) + (v.z * v.z + v.w * v.w);
    }
#pragma unroll
    for (int off = 32; off >= 1; off >>= 1) {
        s += __shfl_xor(s, off);
        ss += __shfl_xor(ss, off);
    }
    __shared__ float red[8];
    __shared__ float sw[16], sb[16];
    int wave = t >> 6;
    if ((t & 63) == 0) { red[wave] = s; red[wave + 4] = ss; }
    if (t < 16) { sw[t] = gnw[g * 16 + t]; sb[t] = gnb[g * 16 + t]; }
    __syncthreads();
    float S = red[0] + red[1] + red[2] + red[3];
    float SS = red[4] + red[5] + red[6] + red[7];
    float mean = S * (1.0f / 16384.0f);
    float var = SS * (1.0f / 16384.0f) - mean * mean;
    float rstd = rsqrtf(var + 1e-5f);

    __shared__ ushort tile[16][258];
    int cc0 = (t & 3) * 4;
    int nb = t >> 2;
    for (int chunk = 0; chunk < 4; ++chunk) {
        __syncthreads();
#pragma unroll
        for (int cc = 0; cc < 16; ++cc) {
            float v = xp[cc * 1024 + chunk * 256 + t];
            tile[cc][t] = f2bf((v - mean) * rstd * sw[cc] + sb[cc]);
        }
        __syncthreads();
        size_t rowbase = (size_t)b * 1024 + chunk * 256;
#pragma unroll
        for (int k = 0; k < 4; ++k) {
            int nl = nb + 64 * k;
            ushort4 p;
            p.x = tile[cc0 + 0][nl];
            p.y = tile[cc0 + 1][nl];
            p.z = tile[cc0 + 2][nl];
            p.w = tile[cc0 + 3][nl];
            *(ushort4*)(hnT + (rowbase + nl) * 512 + g * 16 + cc0) = p;
        }
    }
}

// ---------------------------------------------------------------- QKV GEMM
// linear grid 768; XCD swizzle: b = i&7 (one batch per XCD -> hnT[b]+W L2-resident)
// Q outputs pre-scaled by CS so attention computes exp2(S) directly.
__global__ __launch_bounds__(256) void gemm_qkv(const ushort* __restrict__ Wb,
                                                const ushort* __restrict__ hnT,
                                                const float* __restrict__ qkvb,
                                                ushort* __restrict__ qT,
                                                ushort* __restrict__ kT,
                                                ushort* __restrict__ vb) {
    int lane = threadIdx.x & 63, wave = threadIdx.x >> 6;
    int l15 = lane & 15, lg = lane >> 4;
    int bi = blockIdx.x;
    int b = bi & 7;
    int slot = bi >> 3;            // 0..95
    int m0 = (slot % 12) * 128;
    int n0 = (slot / 12) * 128;
    int mw = (wave >> 1) * 64, nw = (wave & 1) * 64;
    const ushort* bb = hnT + (size_t)b * 524288;

    __shared__ ushort abuf[2][8192];
    __shared__ ushort bbuf[2][8192];

    f32x4 acc[4][4] = {};
    stage_tile64(abuf[0], Wb + (size_t)m0 * 512, 512, 16, wave, lane);
    stage_tile64(bbuf[0], bb + (size_t)n0 * 512, 512, 16, wave, lane);
    __syncthreads();
    int cur = 0;
#pragma unroll 1
    for (int t = 0; t < 8; ++t) {
        if (t < 7) {
            stage_tile64(abuf[cur ^ 1], Wb + (size_t)m0 * 512 + (t + 1) * 64, 512, 16, wave, lane);
            stage_tile64(bbuf[cur ^ 1], bb + (size_t)n0 * 512 + (t + 1) * 64, 512, 16, wave, lane);
        }
#pragma unroll
        for (int kh = 0; kh < 2; kh++) {
            bf16x8 af[4], bfr[4];
#pragma unroll
            for (int i = 0; i < 4; i++)
                af[i] = lds_read_row(abuf[cur], mw + i * 16 + l15, kh * 64 + lg * 16);
#pragma unroll
            for (int j = 0; j < 4; j++)
                bfr[j] = lds_read_row(bbuf[cur], nw + j * 16 + l15, kh * 64 + lg * 16);
#pragma unroll
            for (int i = 0; i < 4; i++)
#pragma unroll
                for (int j = 0; j < 4; j++)
                    acc[i][j] = MFMA(af[i], bfr[j], acc[i][j]);
        }
        __syncthreads();
        cur ^= 1;
    }

#pragma unroll
    for (int i = 0; i < 4; i++) {
        int ob = m0 + mw + i * 16 + lg * 4;
        float bias[4];
#pragma unroll
        for (int r = 0; r < 4; r++) bias[r] = qkvb[ob + r];
        int part = ob >> 9;
        int oo = ob & 511;
#pragma unroll
        for (int j = 0; j < 4; j++) {
            int n = n0 + nw + j * 16 + l15;
            if (part == 2) {
#pragma unroll
                for (int r = 0; r < 4; r++)
                    vb[(size_t)(b * 512 + oo + r) * 1024 + n] = f2bf(acc[i][j][r] + bias[r]);
            } else {
                ushort* dst = part ? kT : qT;
                float sc = part ? 1.0f : CS;      // pre-scale Q by 0.125*log2(e)
                int h = oo >> 6, dd = oo & 63;
                ushort4 p;
                p.x = f2bf((acc[i][j][0] + bias[0]) * sc);
                p.y = f2bf((acc[i][j][1] + bias[1]) * sc);
                p.z = f2bf((acc[i][j][2] + bias[2]) * sc);
                p.w = f2bf((acc[i][j][3] + bias[3]) * sc);
                *(ushort4*)(dst + ((size_t)((b * 8 + h) * 1024 + n)) * 64 + dd) = p;
            }
        }
    }
}

// ---------------------------------------------------------------- attention
// 64 q-rows/block (4 waves x 16 rows) -> grid 1024 = 4 blocks/CU so blocks'
// MFMA and softmax phases overlap across blocks. XCD swizzle: all 16 q-blocks
// of a bh share bi&7 -> same XCD; per-XCD K/V set ~2MB, L2-resident.
// Q pre-scaled: P = exp2(S). Row sums via ones-MFMA.
__global__ __launch_bounds__(256) void attn_kernel(const ushort* __restrict__ qT,
                                                   const ushort* __restrict__ kT,
                                                   const ushort* __restrict__ vb,
                                                   ushort* __restrict__ aoT) {
    int bi = blockIdx.x;
    int bh = ((bi >> 7) << 3) | (bi & 7);
    int q0 = ((bi >> 3) & 15) * 64;
    int b = bh >> 3, h = bh & 7;
    int lane = threadIdx.x & 63, wave = threadIdx.x >> 6;
    int l15 = lane & 15, lg = lane >> 4;
    const ushort* qp = qT + (size_t)bh * 65536;
    const ushort* kp = kT + (size_t)bh * 65536;
    const ushort* vp = vb + (size_t)bh * 65536;

    __shared__ ushort kbuf[2][4096];   // [kv 64][d 64]
    __shared__ ushort vbuf[2][4096];   // [dd 64][kv 64]
    __shared__ ushort pbuf[4][1024];   // per-wave [q 16][kv 64]
    ushort* pw = pbuf[wave];

    bf16x8 vone;
#pragma unroll
    for (int e = 0; e < 8; e++) vone[e] = (__bf16)1.0f;

    bf16x8 qf[2];
#pragma unroll
    for (int kh = 0; kh < 2; kh++)
        qf[kh] = *(const bf16x8*)(qp + (size_t)(q0 + wave * 16 + l15) * 64 + kh * 32 + lg * 8);

    f32x4 oacc[4] = {};
    f32x4 lacc = {};

    stage_tile64(kbuf[0], kp, 64, 8, wave, lane);
    stage_tile64(vbuf[0], vp, 1024, 8, wave, lane);
    __syncthreads();
    int cur = 0;

#pragma unroll 1
    for (int t = 0; t < 16; ++t) {
        if (t < 15) {
            stage_tile64(kbuf[cur ^ 1], kp + (size_t)(t + 1) * 4096, 64, 8, wave, lane);
            stage_tile64(vbuf[cur ^ 1], vp + (t + 1) * 64, 1024, 8, wave, lane);
        }
        const ushort* kb = kbuf[cur];
        const ushort* vc = vbuf[cur];

        f32x4 sacc[4] = {};
        __builtin_amdgcn_s_setprio(1);
#pragma unroll
        for (int kh = 0; kh < 2; kh++)
#pragma unroll
            for (int cf = 0; cf < 4; cf++) {
                bf16x8 kf = lds_read_row(kb, cf * 16 + l15, kh * 64 + lg * 16);
                sacc[cf] = MFMA(qf[kh], kf, sacc[cf]);
            }
        __builtin_amdgcn_s_setprio(0);

        // hoisted V fragments (independent of P) - ds latency hides under exp
        bf16x8 vf[2][4];
#pragma unroll
        for (int ks = 0; ks < 2; ks++)
#pragma unroll
            for (int cf = 0; cf < 4; cf++)
                vf[ks][cf] = lds_read_row(vc, cf * 16 + l15, ks * 64 + lg * 16);

        // P = exp2(S) (Q pre-scaled); bf16 P to swizzled per-wave LDS
#pragma unroll
        for (int cf = 0; cf < 4; cf++)
#pragma unroll
            for (int r = 0; r < 4; r++) {
                float p = exp2f(sacc[cf][r]);
                int row = lg * 4 + r;
                int cb = (cf * 16 + l15) * 2;
                *(__bf16*)((char*)pw + row * 128 + (cb ^ ((row & 7) << 4))) = (__bf16)p;
            }

        __builtin_amdgcn_s_setprio(1);
#pragma unroll
        for (int ks = 0; ks < 2; ks++) {
            bf16x8 pf = lds_read_row(pw, l15, ks * 64 + lg * 16);
            lacc = MFMA(pf, vone, lacc);         // row sums on matrix pipe
#pragma unroll
            for (int cf = 0; cf < 4; cf++)
                oacc[cf] = MFMA(pf, vf[ks][cf], oacc[cf]);
        }
        __builtin_amdgcn_s_setprio(0);
        __syncthreads();
        cur ^= 1;
    }

#pragma unroll
    for (int r = 0; r < 4; r++) {
        float inv = 1.0f / lacc[r];
        int n = q0 + wave * 16 + lg * 4 + r;
        size_t obase = ((size_t)b * 1024 + n) * 512 + h * 64;
#pragma unroll
        for (int cf = 0; cf < 4; cf++)
            aoT[obase + cf * 16 + l15] = f2bf(oacc[cf][r] * inv);
    }
}

// ---------------------------------------------------------------- proj GEMM + residual
// linear grid 512; XCD swizzle: b = i&7
__global__ __launch_bounds__(256) void gemm_proj(const ushort* __restrict__ Wb,
                                                 const ushort* __restrict__ aoT,
                                                 const float* __restrict__ projb,
                                                 const float* __restrict__ x,
                                                 float* __restrict__ out) {
    int lane = threadIdx.x & 63, wave = threadIdx.x >> 6;
    int l15 = lane & 15, lg = lane >> 4;
    int bi = blockIdx.x;
    int b = bi & 7;
    int slot = bi >> 3;            // 0..63
    int m0 = (slot & 3) * 128;
    int n0 = (slot >> 2) * 64;
    int mw = (wave >> 1) * 64, nw = (wave & 1) * 32;
    const ushort* bb = aoT + (size_t)b * 524288;

    __shared__ ushort abuf[2][8192];   // 128 x 64
    __shared__ ushort bbuf[2][4096];   // 64 x 64

    f32x4 acc[4][2] = {};
    stage_tile64(abuf[0], Wb + (size_t)m0 * 512, 512, 16, wave, lane);
    stage_tile64(bbuf[0], bb + (size_t)n0 * 512, 512, 8, wave, lane);
    __syncthreads();
    int cur = 0;
#pragma unroll 1
    for (int t = 0; t < 8; ++t) {
        if (t < 7) {
            stage_tile64(abuf[cur ^ 1], Wb + (size_t)m0 * 512 + (t + 1) * 64, 512, 16, wave, lane);
            stage_tile64(bbuf[cur ^ 1], bb + (size_t)n0 * 512 + (t + 1) * 64, 512, 8, wave, lane);
        }
#pragma unroll
        for (int kh = 0; kh < 2; kh++) {
            bf16x8 af[4], bfr[2];
#pragma unroll
            for (int i = 0; i < 4; i++)
                af[i] = lds_read_row(abuf[cur], mw + i * 16 + l15, kh * 64 + lg * 16);
#pragma unroll
            for (int j = 0; j < 2; j++)
                bfr[j] = lds_read_row(bbuf[cur], nw + j * 16 + l15, kh * 64 + lg * 16);
#pragma unroll
            for (int i = 0; i < 4; i++)
#pragma unroll
                for (int j = 0; j < 2; j++)
                    acc[i][j] = MFMA(af[i], bfr[j], acc[i][j]);
        }
        __syncthreads();
        cur ^= 1;
    }

#pragma unroll
    for (int i = 0; i < 4; i++) {
        int ob = m0 + mw + i * 16 + lg * 4;
        float bias[4];
#pragma unroll
        for (int r = 0; r < 4; r++) bias[r] = projb[ob + r];
#pragma unroll
        for (int j = 0; j < 2; j++) {
            int n = n0 + nw + j * 16 + l15;
#pragma unroll
            for (int r = 0; r < 4; r++) {
                size_t idx = (size_t)(b * 512 + ob + r) * 1024 + n;
                out[idx] = x[idx] + bias[r] + acc[i][j][r];
            }
        }
    }
}

// ---------------------------------------------------------------- launcher
extern "C" void kernel_launch(void* const* d_in, const int* in_sizes, int n_in,
                              void* d_out, int out_size, void* d_ws, size_t ws_size,
                              hipStream_t stream) {
    const float* x     = (const float*)d_in[0];
    const float* gnw   = (const float*)d_in[1];
    const float* gnb   = (const float*)d_in[2];
    const float* qkvw  = (const float*)d_in[3];
    const float* qkvb  = (const float*)d_in[4];
    const float* projw = (const float*)d_in[5];
    const float* projb = (const float*)d_in[6];
    float* out = (float*)d_out;

    char* ws = (char*)d_ws;
    ushort* hnT    = (ushort*)(ws);                          // 8 MB (reused as aoT)
    ushort* qT     = (ushort*)(ws + (size_t)(8u << 20));     // 8 MB
    ushort* kT     = (ushort*)(ws + (size_t)(16u << 20));    // 8 MB
    ushort* vbuf   = (ushort*)(ws + (size_t)(24u << 20));    // 8 MB
    ushort* qkvwb  = (ushort*)(ws + (size_t)(32u << 20));    // 1.5 MB
    ushort* projwb = (ushort*)(ws + (size_t)(32u << 20) + 1572864);  // 0.5 MB

    gn_cvt_kernel<<<dim3(1280), dim3(256), 0, stream>>>(x, gnw, gnb, hnT,
                                                        qkvw, projw, qkvwb, projwb);
    gemm_qkv<<<dim3(768), dim3(256), 0, stream>>>(qkvwb, hnT, qkvb, qT, kT, vbuf);
    attn_kernel<<<dim3(1024), dim3(256), 0, stream>>>(qT, kT, vbuf, hnT /* aoT */);
    gemm_proj<<<dim3(512), dim3(256), 0, stream>>>(projwb, hnT, projb, x, out);
}

// Round 7
// 89.832 us; speedup vs baseline: 1.1089x; 1.1089x over previous
//
#include <hip/hip_runtime.h>

typedef __bf16 bf16x8 __attribute__((ext_vector_type(8)));
typedef __bf16 bf16x4 __attribute__((ext_vector_type(4)));
typedef float f32x4 __attribute__((ext_vector_type(4)));

#define MFMA(a, b, c) __builtin_amdgcn_mfma_f32_16x16x32_bf16(a, b, c, 0, 0, 0)

#define CS 0.18033688011112042f   /* 0.125 * log2(e) */

__device__ __forceinline__ ushort f2bf(float f) {
    __bf16 h = (__bf16)f;
    return *(ushort*)&h;
}

// ---- stage an (8*nchunks)-row x 64-col bf16 tile into LDS, XOR-swizzled ----
// LDS dest linear (global_load_lds requirement); per-lane GLOBAL source address
// pre-swizzled (m173 pattern). One 1KB chunk (8 rows x 128B) per wave-instr.
__device__ __forceinline__ void stage_tile64(ushort* lds, const ushort* gbase,
                                             int row_stride, int nchunks,
                                             int wave, int lane) {
    int r8 = lane >> 3;                       // row within 8-row chunk
    int cswz = ((lane & 7) ^ r8) << 4;        // pre-swizzled source byte col
#pragma unroll
    for (int c = wave; c < nchunks; c += 4) {
        const char* g = (const char*)(gbase + (size_t)(c * 8 + r8) * row_stride) + cswz;
        __builtin_amdgcn_global_load_lds(
            (const __attribute__((address_space(1))) unsigned int*)g,
            (__attribute__((address_space(3))) unsigned int*)((char*)lds + c * 1024),
            16, 0, 0);
    }
}

// swizzled read of logical (row, col-byte cb), 16B
__device__ __forceinline__ bf16x8 lds_read_row(const ushort* lds, int row, int cb) {
    return *(const bf16x8*)((const char*)lds + row * 128 + (cb ^ ((row & 7) << 4)));
}

// ---------------------------------------------------------------- groupnorm (+fused weight cvt)
// blocks [0,256): GroupNorm per (b,g); blocks [256,1280): fp32->bf16 weight cvt
__global__ __launch_bounds__(256) void gn_cvt_kernel(const float* __restrict__ x,
                                                     const float* __restrict__ gnw,
                                                     const float* __restrict__ gnb,
                                                     ushort* __restrict__ hnT,
                                                     const float* __restrict__ w1,
                                                     const float* __restrict__ w2,
                                                     ushort* __restrict__ o1,
                                                     ushort* __restrict__ o2) {
    if (blockIdx.x >= 256) {
        int t = (blockIdx.x - 256) * 256 + threadIdx.x;
        const int n1q = (1536 * 512) / 4;
        float4 v;
        ushort* dst;
        int idx;
        if (t < n1q) {
            v = ((const float4*)w1)[t]; dst = o1; idx = t;
        } else {
            idx = t - n1q;
            v = ((const float4*)w2)[idx]; dst = o2;
        }
        ushort4 p;
        p.x = f2bf(v.x); p.y = f2bf(v.y); p.z = f2bf(v.z); p.w = f2bf(v.w);
        ((ushort4*)dst)[idx] = p;
        return;
    }

    int b = blockIdx.x >> 5, g = blockIdx.x & 31;
    const float* xp = x + (size_t)(b * 512 + g * 16) * 1024;
    int t = threadIdx.x;

    float s = 0.f, ss = 0.f;
    const float4* xp4 = (const float4*)xp;
    for (int i = t; i < 4096; i += 256) {
        float4 v = xp4[i];
        s += (v.x + v.y) + (v.z + v.w);
        ss += (v.x * v.x + v.y * v.y) + (v.z * v.z + v.w * v.w);
    }
#pragma unroll
    for (int off = 32; off >= 1; off >>= 1) {
        s += __shfl_xor(s, off);
        ss += __shfl_xor(ss, off);
    }
    __shared__ float red[8];
    __shared__ float sw[16], sb[16];
    int wave = t >> 6;
    if ((t & 63) == 0) { red[wave] = s; red[wave + 4] = ss; }
    if (t < 16) { sw[t] = gnw[g * 16 + t]; sb[t] = gnb[g * 16 + t]; }
    __syncthreads();
    float S = red[0] + red[1] + red[2] + red[3];
    float SS = red[4] + red[5] + red[6] + red[7];
    float mean = S * (1.0f / 16384.0f);
    float var = SS * (1.0f / 16384.0f) - mean * mean;
    float rstd = rsqrtf(var + 1e-5f);

    __shared__ ushort tile[16][258];
    int cc0 = (t & 3) * 4;
    int nb = t >> 2;
    for (int chunk = 0; chunk < 4; ++chunk) {
        __syncthreads();
#pragma unroll
        for (int cc = 0; cc < 16; ++cc) {
            float v = xp[cc * 1024 + chunk * 256 + t];
            tile[cc][t] = f2bf((v - mean) * rstd * sw[cc] + sb[cc]);
        }
        __syncthreads();
        size_t rowbase = (size_t)b * 1024 + chunk * 256;
#pragma unroll
        for (int k = 0; k < 4; ++k) {
            int nl = nb + 64 * k;
            ushort4 p;
            p.x = tile[cc0 + 0][nl];
            p.y = tile[cc0 + 1][nl];
            p.z = tile[cc0 + 2][nl];
            p.w = tile[cc0 + 3][nl];
            *(ushort4*)(hnT + (rowbase + nl) * 512 + g * 16 + cc0) = p;
        }
    }
}

// ---------------------------------------------------------------- QKV GEMM
// linear grid 768; XCD swizzle: b = i&7 (one batch per XCD -> hnT[b]+W L2-resident)
// Q outputs pre-scaled by CS so attention computes exp2(S) directly.
// V written with kv-axis permuted within each 64-token block:
//   n' = 4*(n&15) + ((n>>4)&3)  -- matches attention's packed-P layout.
__global__ __launch_bounds__(256) void gemm_qkv(const ushort* __restrict__ Wb,
                                                const ushort* __restrict__ hnT,
                                                const float* __restrict__ qkvb,
                                                ushort* __restrict__ qT,
                                                ushort* __restrict__ kT,
                                                ushort* __restrict__ vb) {
    int lane = threadIdx.x & 63, wave = threadIdx.x >> 6;
    int l15 = lane & 15, lg = lane >> 4;
    int bi = blockIdx.x;
    int b = bi & 7;
    int slot = bi >> 3;            // 0..95
    int m0 = (slot % 12) * 128;
    int n0 = (slot / 12) * 128;
    int mw = (wave >> 1) * 64, nw = (wave & 1) * 64;
    const ushort* bb = hnT + (size_t)b * 524288;

    __shared__ ushort abuf[2][8192];
    __shared__ ushort bbuf[2][8192];

    f32x4 acc[4][4] = {};
    stage_tile64(abuf[0], Wb + (size_t)m0 * 512, 512, 16, wave, lane);
    stage_tile64(bbuf[0], bb + (size_t)n0 * 512, 512, 16, wave, lane);
    __syncthreads();
    int cur = 0;
#pragma unroll 1
    for (int t = 0; t < 8; ++t) {
        if (t < 7) {
            stage_tile64(abuf[cur ^ 1], Wb + (size_t)m0 * 512 + (t + 1) * 64, 512, 16, wave, lane);
            stage_tile64(bbuf[cur ^ 1], bb + (size_t)n0 * 512 + (t + 1) * 64, 512, 16, wave, lane);
        }
#pragma unroll
        for (int kh = 0; kh < 2; kh++) {
            bf16x8 af[4], bfr[4];
#pragma unroll
            for (int i = 0; i < 4; i++)
                af[i] = lds_read_row(abuf[cur], mw + i * 16 + l15, kh * 64 + lg * 16);
#pragma unroll
            for (int j = 0; j < 4; j++)
                bfr[j] = lds_read_row(bbuf[cur], nw + j * 16 + l15, kh * 64 + lg * 16);
#pragma unroll
            for (int i = 0; i < 4; i++)
#pragma unroll
                for (int j = 0; j < 4; j++)
                    acc[i][j] = MFMA(af[i], bfr[j], acc[i][j]);
        }
        __syncthreads();
        cur ^= 1;
    }

#pragma unroll
    for (int i = 0; i < 4; i++) {
        int ob = m0 + mw + i * 16 + lg * 4;
        float bias[4];
#pragma unroll
        for (int r = 0; r < 4; r++) bias[r] = qkvb[ob + r];
        int part = ob >> 9;
        int oo = ob & 511;
#pragma unroll
        for (int j = 0; j < 4; j++) {
            int n = n0 + nw + j * 16 + l15;
            if (part == 2) {
                int np = (n & ~63) | (((n & 15) << 2) | ((n >> 4) & 3));
#pragma unroll
                for (int r = 0; r < 4; r++)
                    vb[(size_t)(b * 512 + oo + r) * 1024 + np] = f2bf(acc[i][j][r] + bias[r]);
            } else {
                ushort* dst = part ? kT : qT;
                float sc = part ? 1.0f : CS;      // pre-scale Q by 0.125*log2(e)
                int h = oo >> 6, dd = oo & 63;
                ushort4 p;
                p.x = f2bf((acc[i][j][0] + bias[0]) * sc);
                p.y = f2bf((acc[i][j][1] + bias[1]) * sc);
                p.z = f2bf((acc[i][j][2] + bias[2]) * sc);
                p.w = f2bf((acc[i][j][3] + bias[3]) * sc);
                *(ushort4*)(dst + ((size_t)((b * 8 + h) * 1024 + n)) * 64 + dd) = p;
            }
        }
    }
}

// ---------------------------------------------------------------- attention
// 128 q-rows/block (4 waves x 32 rows); K/V 64-row tiles double-buffered in LDS.
// XCD swizzle: all 8 q-blocks of a bh share bi&7 -> same XCD (K/V L2-resident).
// Q pre-scaled: P = exp2(S). Row sums via ones-MFMA. P stored packed: each
// lane's 4 P values (cf=0..3 of one row) are adjacent under the kv-permutation
// k' = 4*(kv&15) + (kv>>4) -> single bf16x4 ds_write_b64 per (i,r); V was
// written by gemm_qkv in the same permuted order, so PV contraction matches.
__global__ __launch_bounds__(256) void attn_kernel(const ushort* __restrict__ qT,
                                                   const ushort* __restrict__ kT,
                                                   const ushort* __restrict__ vb,
                                                   ushort* __restrict__ aoT) {
    int bi = blockIdx.x;
    int bh = ((bi >> 6) << 3) | (bi & 7);
    int q0 = ((bi >> 3) & 7) * 128;
    int b = bh >> 3, h = bh & 7;
    int lane = threadIdx.x & 63, wave = threadIdx.x >> 6;
    int l15 = lane & 15, lg = lane >> 4;
    const ushort* qp = qT + (size_t)bh * 65536;
    const ushort* kp = kT + (size_t)bh * 65536;
    const ushort* vp = vb + (size_t)bh * 65536;

    __shared__ ushort kbuf[2][4096];   // [kv 64][d 64]
    __shared__ ushort vbuf[2][4096];   // [dd 64][kv' 64] (kv permuted)
    __shared__ ushort pbuf[4][2048];   // per-wave [q 32][kv' 64]
    ushort* pw = pbuf[wave];

    bf16x8 vone;
#pragma unroll
    for (int e = 0; e < 8; e++) vone[e] = (__bf16)1.0f;

    bf16x8 qf[2][2];
#pragma unroll
    for (int i = 0; i < 2; i++)
#pragma unroll
        for (int kh = 0; kh < 2; kh++)
            qf[i][kh] = *(const bf16x8*)(qp + (size_t)(q0 + wave * 32 + i * 16 + l15) * 64 + kh * 32 + lg * 8);

    f32x4 oacc[2][4] = {};
    f32x4 lacc[2] = {};

    stage_tile64(kbuf[0], kp, 64, 8, wave, lane);
    stage_tile64(vbuf[0], vp, 1024, 8, wave, lane);
    __syncthreads();
    int cur = 0;

#pragma unroll 1
    for (int t = 0; t < 16; ++t) {
        if (t < 15) {
            stage_tile64(kbuf[cur ^ 1], kp + (size_t)(t + 1) * 4096, 64, 8, wave, lane);
            stage_tile64(vbuf[cur ^ 1], vp + (t + 1) * 64, 1024, 8, wave, lane);
        }
        const ushort* kb = kbuf[cur];
        const ushort* vc = vbuf[cur];

        f32x4 sacc[2][4] = {};
        __builtin_amdgcn_s_setprio(1);
#pragma unroll
        for (int kh = 0; kh < 2; kh++)
#pragma unroll
            for (int cf = 0; cf < 4; cf++) {
                bf16x8 kf = lds_read_row(kb, cf * 16 + l15, kh * 64 + lg * 16);
                sacc[0][cf] = MFMA(qf[0][kh], kf, sacc[0][cf]);
                sacc[1][cf] = MFMA(qf[1][kh], kf, sacc[1][cf]);
            }
        __builtin_amdgcn_s_setprio(0);

        // hoisted V fragments (independent of P) - ds latency hides under exp
        bf16x8 vf[2][4];
#pragma unroll
        for (int ks = 0; ks < 2; ks++)
#pragma unroll
            for (int cf = 0; cf < 4; cf++)
                vf[ks][cf] = lds_read_row(vc, cf * 16 + l15, ks * 64 + lg * 16);

        // P = exp2(S); pack 4 bf16 (cf=0..3, one row) -> one ds_write_b64
#pragma unroll
        for (int i = 0; i < 2; i++)
#pragma unroll
            for (int r = 0; r < 4; r++) {
                bf16x4 pq;
                pq[0] = (__bf16)exp2f(sacc[i][0][r]);
                pq[1] = (__bf16)exp2f(sacc[i][1][r]);
                pq[2] = (__bf16)exp2f(sacc[i][2][r]);
                pq[3] = (__bf16)exp2f(sacc[i][3][r]);
                int row = i * 16 + lg * 4 + r;
                *(bf16x4*)((char*)pw + row * 128 + ((l15 * 8) ^ ((row & 7) << 4))) = pq;
            }

        __builtin_amdgcn_s_setprio(1);
#pragma unroll
        for (int i = 0; i < 2; i++)
#pragma unroll
            for (int ks = 0; ks < 2; ks++) {
                bf16x8 pf = lds_read_row(pw, i * 16 + l15, ks * 64 + lg * 16);
                lacc[i] = MFMA(pf, vone, lacc[i]);   // row sums on matrix pipe
#pragma unroll
                for (int cf = 0; cf < 4; cf++)
                    oacc[i][cf] = MFMA(pf, vf[ks][cf], oacc[i][cf]);
            }
        __builtin_amdgcn_s_setprio(0);
        __syncthreads();
        cur ^= 1;
    }

#pragma unroll
    for (int i = 0; i < 2; i++)
#pragma unroll
        for (int r = 0; r < 4; r++) {
            float inv = 1.0f / lacc[i][r];
            int n = q0 + wave * 32 + i * 16 + lg * 4 + r;
            size_t obase = ((size_t)b * 1024 + n) * 512 + h * 64;
#pragma unroll
            for (int cf = 0; cf < 4; cf++)
                aoT[obase + cf * 16 + l15] = f2bf(oacc[i][cf][r] * inv);
        }
}

// ---------------------------------------------------------------- proj GEMM + residual
// linear grid 512; XCD swizzle: b = i&7
__global__ __launch_bounds__(256) void gemm_proj(const ushort* __restrict__ Wb,
                                                 const ushort* __restrict__ aoT,
                                                 const float* __restrict__ projb,
                                                 const float* __restrict__ x,
                                                 float* __restrict__ out) {
    int lane = threadIdx.x & 63, wave = threadIdx.x >> 6;
    int l15 = lane & 15, lg = lane >> 4;
    int bi = blockIdx.x;
    int b = bi & 7;
    int slot = bi >> 3;            // 0..63
    int m0 = (slot & 3) * 128;
    int n0 = (slot >> 2) * 64;
    int mw = (wave >> 1) * 64, nw = (wave & 1) * 32;
    const ushort* bb = aoT + (size_t)b * 524288;

    __shared__ ushort abuf[2][8192];   // 128 x 64
    __shared__ ushort bbuf[2][4096];   // 64 x 64

    f32x4 acc[4][2] = {};
    stage_tile64(abuf[0], Wb + (size_t)m0 * 512, 512, 16, wave, lane);
    stage_tile64(bbuf[0], bb + (size_t)n0 * 512, 512, 8, wave, lane);
    __syncthreads();
    int cur = 0;
#pragma unroll 1
    for (int t = 0; t < 8; ++t) {
        if (t < 7) {
            stage_tile64(abuf[cur ^ 1], Wb + (size_t)m0 * 512 + (t + 1) * 64, 512, 16, wave, lane);
            stage_tile64(bbuf[cur ^ 1], bb + (size_t)n0 * 512 + (t + 1) * 64, 512, 8, wave, lane);
        }
#pragma unroll
        for (int kh = 0; kh < 2; kh++) {
            bf16x8 af[4], bfr[2];
#pragma unroll
            for (int i = 0; i < 4; i++)
                af[i] = lds_read_row(abuf[cur], mw + i * 16 + l15, kh * 64 + lg * 16);
#pragma unroll
            for (int j = 0; j < 2; j++)
                bfr[j] = lds_read_row(bbuf[cur], nw + j * 16 + l15, kh * 64 + lg * 16);
#pragma unroll
            for (int i = 0; i < 4; i++)
#pragma unroll
                for (int j = 0; j < 2; j++)
                    acc[i][j] = MFMA(af[i], bfr[j], acc[i][j]);
        }
        __syncthreads();
        cur ^= 1;
    }

#pragma unroll
    for (int i = 0; i < 4; i++) {
        int ob = m0 + mw + i * 16 + lg * 4;
        float bias[4];
#pragma unroll
        for (int r = 0; r < 4; r++) bias[r] = projb[ob + r];
#pragma unroll
        for (int j = 0; j < 2; j++) {
            int n = n0 + nw + j * 16 + l15;
#pragma unroll
            for (int r = 0; r < 4; r++) {
                size_t idx = (size_t)(b * 512 + ob + r) * 1024 + n;
                out[idx] = x[idx] + bias[r] + acc[i][j][r];
            }
        }
    }
}

// ---------------------------------------------------------------- launcher
extern "C" void kernel_launch(void* const* d_in, const int* in_sizes, int n_in,
                              void* d_out, int out_size, void* d_ws, size_t ws_size,
                              hipStream_t stream) {
    const float* x     = (const float*)d_in[0];
    const float* gnw   = (const float*)d_in[1];
    const float* gnb   = (const float*)d_in[2];
    const float* qkvw  = (const float*)d_in[3];
    const float* qkvb  = (const float*)d_in[4];
    const float* projw = (const float*)d_in[5];
    const float* projb = (const float*)d_in[6];
    float* out = (float*)d_out;

    char* ws = (char*)d_ws;
    ushort* hnT    = (ushort*)(ws);                          // 8 MB (reused as aoT)
    ushort* qT     = (ushort*)(ws + (size_t)(8u << 20));     // 8 MB
    ushort* kT     = (ushort*)(ws + (size_t)(16u << 20));    // 8 MB
    ushort* vbuf   = (ushort*)(ws + (size_t)(24u << 20));    // 8 MB
    ushort* qkvwb  = (ushort*)(ws + (size_t)(32u << 20));    // 1.5 MB
    ushort* projwb = (ushort*)(ws + (size_t)(32u << 20) + 1572864);  // 0.5 MB

    gn_cvt_kernel<<<dim3(1280), dim3(256), 0, stream>>>(x, gnw, gnb, hnT,
                                                        qkvw, projw, qkvwb, projwb);
    gemm_qkv<<<dim3(768), dim3(256), 0, stream>>>(qkvwb, hnT, qkvb, qT, kT, vbuf);
    attn_kernel<<<dim3(512), dim3(256), 0, stream>>>(qT, kT, vbuf, hnT /* aoT */);
    gemm_proj<<<dim3(512), dim3(256), 0, stream>>>(projwb, hnT, projb, x, out);
}